// Round 7
// baseline (453.467 us; speedup 1.0000x reference)
//
#include <hip/hip_runtime.h>
#include <hip/hip_bf16.h>
#include <cstdint>
#include <cstddef>

// ---------------- sizes ----------------
#define N1 442368   // 48*96*96 spatial (s1)
#define N2 55296    // 24*48*48 spatial (p2, s2)
#define N3 6912     // 12*24*24 spatial (p3, s3)

// padded fp64 feature layouts; rows are x-parity de-interleaved: [evens][odds]
#define PZ1 9409    // 97*97
#define PN1 461041  // 49*97*97
#define PV1 461041
#define PZ2 2401    // 49*49
#define PN2 60025   // 25*49*49
#define PV2 60025

// logical x -> de-interleaved slot
#define MAP1(x) (((x) & 1) ? 49 + ((x) >> 1) : ((x) >> 1))
#define MAP2(x) (((x) & 1) ? 25 + ((x) >> 1) : ((x) >> 1))

#define KCAND 512
#define CAP   4096

// ---------------- helpers ----------------
__device__ __forceinline__ unsigned long long f2key64(double f) {
  unsigned long long b = (unsigned long long)__double_as_longlong(f);
  return (b & 0x8000000000000000ULL) ? ~b : (b | 0x8000000000000000ULL);
}
__device__ __forceinline__ unsigned f2key32(float f) {
  unsigned b = __float_as_uint(f);
  return (b & 0x80000000u) ? ~b : (b | 0x80000000u);
}

// ---------------- conv1: 1->16ch, in 96x192x192, out padded de-interleaved [16][49][97][97] ----------------
__global__ __launch_bounds__(256) void conv1_k(const float* __restrict__ x, const float* __restrict__ w,
                                               const float* __restrict__ b, double* __restrict__ f1) {
  __shared__ __align__(16) double wsD[27 * 16];  // [t][c]
  for (int i = threadIdx.x; i < 27 * 16; i += 256) {
    int t = i >> 4, c = i & 15;
    wsD[i] = (double)w[c * 27 + t];
  }
  __syncthreads();
  int v = blockIdx.x * 256 + threadIdx.x;
  if (v >= PV1) return;
  int z = v / PZ1; int r = v % PZ1; int y = r / 97; int xo = r % 97;  // logical coords
  int ov = z * PZ1 + y * 97 + MAP1(xo);                              // physical slot
  if (z >= 48 || y >= 96 || xo >= 96) {
#pragma unroll
    for (int c = 0; c < 16; c++) f1[(size_t)c * PN1 + ov] = 0.0;
    return;
  }
  float val[27];
#pragma unroll
  for (int dz = 0; dz < 3; dz++)
#pragma unroll
    for (int dy = 0; dy < 3; dy++)
#pragma unroll
      for (int dx = 0; dx < 3; dx++) {
        int zi = 2 * z + dz, yi = 2 * y + dy, xi = 2 * xo + dx;
        bool ok = (zi < 96) & (yi < 192) & (xi < 192);
        int zc = min(zi, 95), yc = min(yi, 191), xc = min(xi, 191);
        float t = x[(zc * 192 + yc) * 192 + xc];
        val[(dz * 3 + dy) * 3 + dx] = ok ? t : 0.0f;
      }
  double acc[16];
#pragma unroll
  for (int c = 0; c < 16; c++) acc[c] = (double)b[c];
#pragma unroll
  for (int t = 0; t < 27; t++) {
    double vv = (double)val[t];
#pragma unroll
    for (int c = 0; c < 16; c++) acc[c] = fma(vv, wsD[t * 16 + c], acc[c]);
  }
#pragma unroll
  for (int c = 0; c < 16; c++) f1[(size_t)c * PN1 + ov] = fmax(acc[c], 0.0);
}

// ---------------- conv2: 16->32ch; coalesced de-interleaved taps; gridDim.y=2 groups of 16 ----------------
__global__ __launch_bounds__(256) void conv2_k(const double* __restrict__ f1, const float* __restrict__ w,
                                               const float* __restrict__ b, double* __restrict__ f2) {
  __shared__ __align__(16) double wsD[16 * 27 * 16];  // [ci][t][c] 55.3 KB fp64
  int g = blockIdx.y;
  for (int i = threadIdx.x; i < 16 * 27 * 16; i += 256) {
    int ci = i / 432, rem = i % 432, t = rem >> 4, c = rem & 15;
    wsD[i] = (double)w[((size_t)(g * 16 + c) * 16 + ci) * 27 + t];
  }
  __syncthreads();
  int v = blockIdx.x * 256 + threadIdx.x;
  if (v >= PV2) return;
  int z = v / PZ2; int r = v % PZ2; int y = r / 49; int xo = r % 49;  // logical
  int ov = z * PZ2 + y * 49 + MAP2(xo);
  if (z >= 24 || y >= 48 || xo >= 48) {
#pragma unroll
    for (int c = 0; c < 16; c++) f2[(size_t)(g * 16 + c) * PN2 + ov] = 0.0;
    return;
  }
  double acc[16];
#pragma unroll
  for (int c = 0; c < 16; c++) acc[c] = (double)b[g * 16 + c];
  // taps: xin=2x+dx -> slots {x, 49+x, x+1} (all unit-stride across the wave)
  const double* base = f1 + (size_t)(2 * z) * PZ1 + (2 * y) * 97;
  for (int ci = 0; ci < 16; ci++) {
    const double* fp = base + (size_t)ci * PN1;
    double vals[27];
#pragma unroll
    for (int dz = 0; dz < 3; dz++)
#pragma unroll
      for (int dy = 0; dy < 3; dy++) {
        const double* row = fp + dz * PZ1 + dy * 97;
        int o = (dz * 3 + dy) * 3;
        vals[o + 0] = row[xo];
        vals[o + 1] = row[49 + xo];
        vals[o + 2] = row[xo + 1];
      }
#pragma unroll
    for (int t = 0; t < 27; t++) {
      double vv = vals[t];
      const double* wp = &wsD[(ci * 27 + t) * 16];
#pragma unroll
      for (int c = 0; c < 16; c++) acc[c] = fma(vv, wp[c], acc[c]);
    }
  }
#pragma unroll
  for (int c = 0; c < 16; c++) f2[(size_t)(g * 16 + c) * PN2 + ov] = fmax(acc[c], 0.0);
}

// ---------------- conv3: 32->64ch, out [64][6912]; gridDim.y=8 groups of 8 ----------------
__global__ __launch_bounds__(256) void conv3_k(const double* __restrict__ f2, const float* __restrict__ w,
                                               const float* __restrict__ b, double* __restrict__ f3) {
  __shared__ __align__(16) double wsD[32 * 27 * 8];  // [ci][t][c] 55.3 KB fp64
  int g = blockIdx.y;
  for (int i = threadIdx.x; i < 32 * 27 * 8; i += 256) {
    int ci = i / 216, rem = i % 216, t = rem >> 3, c = rem & 7;
    wsD[i] = (double)w[((size_t)(g * 8 + c) * 32 + ci) * 27 + t];
  }
  __syncthreads();
  int v = blockIdx.x * 256 + threadIdx.x;
  if (v >= N3) return;
  int z = v / 576; int r = v % 576; int y = r / 24; int xo = r % 24;
  double acc[8];
#pragma unroll
  for (int c = 0; c < 8; c++) acc[c] = (double)b[g * 8 + c];
  const double* base = f2 + (size_t)(2 * z) * PZ2 + (2 * y) * 49;
  for (int ci = 0; ci < 32; ci++) {
    const double* fp = base + (size_t)ci * PN2;
    double vals[27];
#pragma unroll
    for (int dz = 0; dz < 3; dz++)
#pragma unroll
      for (int dy = 0; dy < 3; dy++) {
        const double* row = fp + dz * PZ2 + dy * 49;
        int o = (dz * 3 + dy) * 3;
        vals[o + 0] = row[xo];
        vals[o + 1] = row[25 + xo];
        vals[o + 2] = row[xo + 1];
      }
#pragma unroll
    for (int t = 0; t < 27; t++) {
      double vv = vals[t];
      const double* wp = &wsD[(ci * 27 + t) * 8];
#pragma unroll
      for (int c = 0; c < 8; c++) acc[c] = fma(vv, wp[c], acc[c]);
    }
  }
#pragma unroll
  for (int c = 0; c < 8; c++) f3[(size_t)(g * 8 + c) * N3 + v] = fmax(acc[c], 0.0);
}

// ---------------- p3 = l3(f3); score3 ----------------
__global__ __launch_bounds__(256) void p3_k(const double* __restrict__ f3, const float* __restrict__ w,
                                            const float* __restrict__ b, double* __restrict__ p3d,
                                            float* __restrict__ p3f, double* __restrict__ s3) {
  __shared__ __align__(16) double wsD[64 * 32];  // [ci][c]
  for (int i = threadIdx.x; i < 64 * 32; i += 256) {
    int ci = i >> 5, c = i & 31;
    wsD[i] = (double)w[c * 64 + ci];
  }
  __syncthreads();
  int v = blockIdx.x * 256 + threadIdx.x;
  if (v >= N3) return;
  double acc[32];
#pragma unroll
  for (int c = 0; c < 32; c++) acc[c] = (double)b[c];
  for (int ci = 0; ci < 64; ci++) {
    double vv = f3[(size_t)ci * N3 + v];
    const double* wp = &wsD[ci * 32];
#pragma unroll
    for (int c = 0; c < 32; c++) acc[c] = fma(vv, wp[c], acc[c]);
  }
  double m = -1e300;
#pragma unroll
  for (int c = 0; c < 32; c++) {
    p3d[(size_t)c * N3 + v] = acc[c];
    p3f[(size_t)c * N3 + v] = (float)acc[c];
    m = fmax(m, acc[c]);
  }
  s3[v] = m;
}

// ---------------- p2 = l2(f2) + up2(p3); score2 ----------------
__global__ __launch_bounds__(256) void p2_k(const double* __restrict__ f2, const float* __restrict__ w,
                                            const float* __restrict__ b, const double* __restrict__ p3d,
                                            double* __restrict__ p2d, float* __restrict__ p2f, double* __restrict__ s2) {
  __shared__ __align__(16) double wsD[32 * 32];  // [ci][c]
  for (int i = threadIdx.x; i < 32 * 32; i += 256) {
    int ci = i >> 5, c = i & 31;
    wsD[i] = (double)w[c * 32 + ci];
  }
  __syncthreads();
  int v = blockIdx.x * 256 + threadIdx.x;
  if (v >= N2) return;
  int z = v / (48 * 48); int r = v % (48 * 48); int y = r / 48; int xo = r % 48;
  int pidx = z * PZ2 + y * 49 + MAP2(xo);
  int up = ((z >> 1) * 24 + (y >> 1)) * 24 + (xo >> 1);
  double acc[32];
#pragma unroll
  for (int c = 0; c < 32; c++) acc[c] = (double)b[c];
  for (int ci = 0; ci < 32; ci++) {
    double vv = f2[(size_t)ci * PN2 + pidx];
    const double* wp = &wsD[ci * 32];
#pragma unroll
    for (int c = 0; c < 32; c++) acc[c] = fma(vv, wp[c], acc[c]);
  }
  double m = -1e300;
#pragma unroll
  for (int c = 0; c < 32; c++) {
    double o = acc[c] + p3d[(size_t)c * N3 + up];
    p2d[(size_t)c * N2 + v] = o;
    p2f[(size_t)c * N2 + v] = (float)o;
    m = fmax(m, o);
  }
  s2[v] = m;
}

// ---------------- p1 score only ----------------
__global__ __launch_bounds__(256) void p1_k(const double* __restrict__ f1, const float* __restrict__ w,
                                            const float* __restrict__ b, const double* __restrict__ p2d,
                                            double* __restrict__ s1) {
  __shared__ __align__(16) double wsD[16 * 32];  // [ci][c]
  for (int i = threadIdx.x; i < 16 * 32; i += 256) {
    int ci = i >> 5, c = i & 31;
    wsD[i] = (double)w[c * 16 + ci];
  }
  __syncthreads();
  int v = blockIdx.x * 256 + threadIdx.x;
  if (v >= N1) return;
  int z = v / (96 * 96); int r = v % (96 * 96); int y = r / 96; int xo = r % 96;
  int pidx = z * PZ1 + y * 97 + MAP1(xo);
  int up = ((z >> 1) * 48 + (y >> 1)) * 48 + (xo >> 1);
  double acc[32];
#pragma unroll
  for (int c = 0; c < 32; c++) acc[c] = (double)b[c];
  for (int ci = 0; ci < 16; ci++) {
    double vv = f1[(size_t)ci * PN1 + pidx];
    const double* wp = &wsD[ci * 32];
#pragma unroll
    for (int c = 0; c < 32; c++) acc[c] = fma(vv, wp[c], acc[c]);
  }
  double m = -1e300;
#pragma unroll
  for (int c = 0; c < 32; c++) m = fmax(m, acc[c] + p2d[(size_t)c * N2 + up]);
  s1[v] = m;
}

// ---------------- selection: two-pass 256-bin radix over fp32 key, batched over levels ----------------
__global__ void hist1_k(const double* __restrict__ s1, const double* __restrict__ s2,
                        const double* __restrict__ s3, unsigned* __restrict__ hist) {
  int L = blockIdx.y;
  const double* s = L == 0 ? s1 : (L == 1 ? s2 : s3);
  int n = L == 0 ? N1 : (L == 1 ? N2 : N3);
  unsigned* hg = hist + L * 256;
  __shared__ unsigned h[256];
  h[threadIdx.x] = 0;
  __syncthreads();
  for (int i = blockIdx.x * 256 + threadIdx.x; i < n; i += gridDim.x * 256)
    atomicAdd(&h[f2key32((float)s[i]) >> 24], 1u);
  __syncthreads();
  unsigned v = h[threadIdx.x];
  if (v) atomicAdd(&hg[threadIdx.x], v);
}

// hist2 computes b1 inline from hist1 (saves a serial launch)
__global__ void hist2_k(const double* __restrict__ s1, const double* __restrict__ s2,
                        const double* __restrict__ s3, const unsigned* __restrict__ hist1,
                        unsigned* __restrict__ hist2) {
  int L = blockIdx.y;
  const double* s = L == 0 ? s1 : (L == 1 ? s2 : s3);
  int n = L == 0 ? N1 : (L == 1 ? N2 : N3);
  const unsigned* h1 = hist1 + L * 256;
  unsigned run = 0; unsigned b1 = 0;
  for (int i = 255; i >= 0; i--) {
    unsigned c = h1[i];
    if (run + c >= (unsigned)KCAND) { b1 = (unsigned)i; break; }
    run += c;
  }
  unsigned* hg = hist2 + L * 256;
  __shared__ unsigned h[256];
  h[threadIdx.x] = 0;
  __syncthreads();
  for (int i = blockIdx.x * 256 + threadIdx.x; i < n; i += gridDim.x * 256) {
    unsigned k = f2key32((float)s[i]);
    if ((k >> 24) == b1) atomicAdd(&h[(k >> 16) & 255u], 1u);
  }
  __syncthreads();
  unsigned v = h[threadIdx.x];
  if (v) atomicAdd(&hg[threadIdx.x], v);
}

// compact computes threshold inline from hist1+hist2 (saves a serial launch)
__global__ void compact_k(const double* __restrict__ s1, const double* __restrict__ s2,
                          const double* __restrict__ s3, const unsigned* __restrict__ hist1,
                          const unsigned* __restrict__ hist2,
                          unsigned long long* __restrict__ ck, unsigned* __restrict__ cidx,
                          unsigned* __restrict__ cnt) {
  int L = blockIdx.y;
  const double* s = L == 0 ? s1 : (L == 1 ? s2 : s3);
  int n = L == 0 ? N1 : (L == 1 ? N2 : N3);
  const unsigned* h1 = hist1 + L * 256;
  const unsigned* h2 = hist2 + L * 256;
  unsigned run = 0; unsigned b1 = 0;
  for (int i = 255; i >= 0; i--) {
    unsigned c = h1[i];
    if (run + c >= (unsigned)KCAND) { b1 = (unsigned)i; break; }
    run += c;
  }
  unsigned b2 = 0;
  for (int i = 255; i >= 0; i--) {
    run += h2[i];
    if (run >= (unsigned)KCAND) { b2 = (unsigned)i; break; }
  }
  unsigned T = (b1 << 24) | (b2 << 16);
  for (int i = blockIdx.x * 256 + threadIdx.x; i < n; i += gridDim.x * 256) {
    double v = s[i];
    if (f2key32((float)v) >= T) {
      unsigned pos = atomicAdd(&cnt[L], 1u);
      if (pos < (unsigned)CAP) {
        ck[(size_t)L * CAP + pos] = f2key64(v);
        cidx[(size_t)L * CAP + pos] = (unsigned)i;
      }
    }
  }
}

// one-block-per-level bitonic sort: (fp64 score desc, idx asc); emits top-512 (idx, valid)
__global__ void sort_k(const unsigned long long* __restrict__ ckA, const unsigned* __restrict__ cidxA,
                       const unsigned* __restrict__ cnt, uint2* __restrict__ topkA) {
  __shared__ unsigned long long k_[CAP];
  __shared__ unsigned x_[CAP];
  int L = blockIdx.x;
  const unsigned long long* ck = ckA + (size_t)L * CAP;
  const unsigned* cidx = cidxA + (size_t)L * CAP;
  uint2* topk = topkA + (size_t)L * KCAND;
  int t = threadIdx.x;
  unsigned m = cnt[L]; if (m > (unsigned)CAP) m = CAP;
  int sz = 512; while (sz < (int)m) sz <<= 1;   // m >= 512 guaranteed
  for (int i = t; i < sz; i += 1024) {
    if (i < (int)m) { k_[i] = ck[i]; x_[i] = cidx[i]; }
    else            { k_[i] = 0ULL;  x_[i] = 0xFFFFFFFFu; }
  }
  __syncthreads();
  for (int kk = 2; kk <= sz; kk <<= 1) {
    for (int j = kk >> 1; j > 0; j >>= 1) {
      for (int i = t; i < sz; i += 1024) {
        int l = i ^ j;
        if (l > i) {
          unsigned long long ka = k_[i], kb = k_[l];
          unsigned ia = x_[i], ib = x_[l];
          bool b_first = (kb > ka) || (kb == ka && ib < ia);
          bool up = (i & kk) == 0;
          if (up == b_first) { k_[i] = kb; x_[i] = ib; k_[l] = ka; x_[l] = ia; }
        }
      }
      __syncthreads();
    }
  }
  if (t < KCAND) {
    unsigned long long key = k_[t];
    unsigned long long bb = (key >> 63) ? (key & 0x7FFFFFFFFFFFFFFFULL) : ~key;
    double sc = __longlong_as_double((long long)bb);
    topk[t] = make_uint2(x_[t], sc > 0.5 ? 1u : 0u);
  }
}

// ---------------- per-candidate cube stats + MLP; L=0 computes cubes on-the-fly ----------------
__global__ __launch_bounds__(64) void mlp_k(const uint2* __restrict__ topkA,
                                            const double* __restrict__ f1d, const double* __restrict__ p2d,
                                            const float* __restrict__ p2f, const float* __restrict__ p3f,
                                            const float* __restrict__ l1w, const float* __restrict__ l1b,
                                            const float* __restrict__ w1, const float* __restrict__ b1,
                                            const float* __restrict__ w2, const float* __restrict__ b2,
                                            float* __restrict__ out) {
  __shared__ double lhi[64];
  __shared__ double f1c[16 * 64];   // [ci][voxel]
  __shared__ double wsD[16 * 32];   // [ci][c]
  int L = blockIdx.y;
  int s = blockIdx.x;
  int D = 48 >> L, H = 96 >> L, W = 96 >> L;
  uint2 e = topkA[(size_t)L * KCAND + s];
  unsigned idx = e.x;
  double valid = e.y ? 1.0 : 0.0;
  int HW = H * W;
  int z = (int)(idx / (unsigned)HW);
  int r = (int)(idx % (unsigned)HW);
  int y = r / W; int x = r % W;
  int zs = min(max(z - 2, 0), D - 4);
  int ys = min(max(y - 2, 0), H - 4);
  int xs = min(max(x - 2, 0), W - 4);
  int t = threadIdx.x;
  int c = t & 31, h = t >> 5;
  double sum = 0.0, ss = 0.0;
  if (L == 0) {
    for (int i = t; i < 512; i += 64) wsD[i] = (double)l1w[(i & 31) * 16 + (i >> 5)];
    for (int i = t; i < 1024; i += 64) {
      int ci = i >> 6, v = i & 63;
      int dz = v >> 4, dy = (v >> 2) & 3, dx = v & 3;
      f1c[i] = f1d[(size_t)ci * PN1 + (zs + dz) * PZ1 + (ys + dy) * 97 + MAP1(xs + dx)];
    }
    __syncthreads();
    double bc = (double)l1b[c];
    for (int i = 0; i < 32; i++) {
      int vv = h * 32 + i;
      int dz = vv >> 4, dy = (vv >> 2) & 3, dx = vv & 3;
      int up = (((zs + dz) >> 1) * 48 + ((ys + dy) >> 1)) * 48 + ((xs + dx) >> 1);
      double val = bc + p2d[(size_t)c * N2 + up];
#pragma unroll
      for (int ci = 0; ci < 16; ci++)
        val = fma(f1c[ci * 64 + vv], wsD[ci * 32 + c], val);
      sum += val; ss = fma(val, val, ss);
    }
  } else {
    const float* p = (L == 1) ? p2f : p3f;
    const float* pc = p + (size_t)c * D * HW;
    for (int i = 0; i < 32; i++) {
      int vv = h * 32 + i;
      int dz = vv >> 4, dy = (vv >> 2) & 3, dx = vv & 3;
      double val = (double)pc[(zs + dz) * HW + (ys + dy) * W + (xs + dx)];
      sum += val; ss = fma(val, val, ss);
    }
  }
  sum += __shfl_xor(sum, 32);
  ss  += __shfl_xor(ss, 32);
  if (h == 0) {
    double mean = sum * (1.0 / 64.0);
    double var = ss * (1.0 / 64.0) - mean * mean;
    lhi[c] = mean;
    lhi[32 + c] = sqrt(var + 1e-6);
  }
  __syncthreads();
  double h0 = (double)b1[t], h1 = (double)b1[t + 64];
  for (int i = 0; i < 64; i++) {
    double li = lhi[i];
    h0 = fma(li, (double)w1[i * 128 + t], h0);
    h1 = fma(li, (double)w1[i * 128 + t + 64], h1);
  }
  h0 = fmax(h0, 0.0); h1 = fmax(h1, 0.0);
  double o0 = h0 * (double)w2[t * 2 + 0] + h1 * (double)w2[(t + 64) * 2 + 0];
  double o1 = h0 * (double)w2[t * 2 + 1] + h1 * (double)w2[(t + 64) * 2 + 1];
  for (int o = 1; o < 64; o <<= 1) { o0 += __shfl_xor(o0, o); o1 += __shfl_xor(o1, o); }
  if (t == 0) {
    out[((size_t)L * KCAND + s) * 2 + 0] = (float)((o0 + (double)b2[0]) * valid);
    out[((size_t)L * KCAND + s) * 2 + 1] = (float)((o1 + (double)b2[1]) * valid);
  }
}

// ---------------- launch ----------------
extern "C" void kernel_launch(void* const* d_in, const int* in_sizes, int n_in,
                              void* d_out, int out_size, void* d_ws, size_t ws_size,
                              hipStream_t stream) {
  const float* x   = (const float*)d_in[0];
  const float* c1w = (const float*)d_in[1];  const float* c1b = (const float*)d_in[2];
  const float* c2w = (const float*)d_in[3];  const float* c2b = (const float*)d_in[4];
  const float* c3w = (const float*)d_in[5];  const float* c3b = (const float*)d_in[6];
  const float* l1w = (const float*)d_in[7];  const float* l1b = (const float*)d_in[8];
  const float* l2w = (const float*)d_in[9];  const float* l2b = (const float*)d_in[10];
  const float* l3w = (const float*)d_in[11]; const float* l3b = (const float*)d_in[12];
  const float* w1  = (const float*)d_in[13]; const float* b1  = (const float*)d_in[14];
  const float* w2  = (const float*)d_in[15]; const float* b2  = (const float*)d_in[16];
  float* out = (float*)d_out;

  char* ws = (char*)d_ws;
  size_t off = 0;
  auto take = [&](size_t bytes) { size_t o = off; off = (off + bytes + 255) & ~(size_t)255; return o; };
  double* f1d = (double*)(ws + take((size_t)16 * PN1 * 8));
  double* f2d = (double*)(ws + take((size_t)32 * PN2 * 8));
  double* f3d = (double*)(ws + take((size_t)64 * N3 * 8));
  double* p2d = (double*)(ws + take((size_t)32 * N2 * 8));
  float*  p2f = (float*) (ws + take((size_t)32 * N2 * 4));
  double* p3d = (double*)(ws + take((size_t)32 * N3 * 8));
  float*  p3f = (float*) (ws + take((size_t)32 * N3 * 4));
  double* s1 = (double*)(ws + take((size_t)N1 * 8));
  double* s2 = (double*)(ws + take((size_t)N2 * 8));
  double* s3 = (double*)(ws + take((size_t)N3 * 8));
  size_t zOff = take((3 * 256 + 3 * 256 + 3) * 4);
  unsigned* hist1 = (unsigned*)(ws + zOff);
  unsigned* hist2 = hist1 + 3 * 256;
  unsigned* cnt   = hist2 + 3 * 256;
  unsigned long long* candKey = (unsigned long long*)(ws + take((size_t)3 * CAP * 8));
  unsigned* candIdx = (unsigned*)(ws + take((size_t)3 * CAP * 4));
  uint2* topk = (uint2*)(ws + take((size_t)3 * KCAND * 8));

  hipMemsetAsync(ws + zOff, 0, (3 * 256 + 3 * 256 + 3) * 4, stream);

  // encoder (fp64, padded + x-de-interleaved intermediates, coalesced taps)
  conv1_k<<<(PV1 + 255) / 256, 256, 0, stream>>>(x, c1w, c1b, f1d);
  conv2_k<<<dim3((PV2 + 255) / 256, 2), 256, 0, stream>>>(f1d, c2w, c2b, f2d);
  conv3_k<<<dim3(N3 / 256, 8), 256, 0, stream>>>(f2d, c3w, c3b, f3d);
  // FPN top-down
  p3_k<<<N3 / 256, 256, 0, stream>>>(f3d, l3w, l3b, p3d, p3f, s3);
  p2_k<<<N2 / 256, 256, 0, stream>>>(f2d, l2w, l2b, p3d, p2d, p2f, s2);
  p1_k<<<N1 / 256, 256, 0, stream>>>(f1d, l1w, l1b, p2d, s1);

  // selection (batched across 3 levels)
  hist1_k<<<dim3(64, 3), 256, 0, stream>>>(s1, s2, s3, hist1);
  hist2_k<<<dim3(64, 3), 256, 0, stream>>>(s1, s2, s3, hist1, hist2);
  compact_k<<<dim3(112, 3), 256, 0, stream>>>(s1, s2, s3, hist1, hist2, candKey, candIdx, cnt);
  sort_k<<<3, 1024, 0, stream>>>(candKey, candIdx, cnt, topk);
  mlp_k<<<dim3(KCAND, 3), 64, 0, stream>>>(topk, f1d, p2d, p2f, p3f, l1w, l1b,
                                           w1, b1, w2, b2, out);
}

// Round 8
// 374.126 us; speedup vs baseline: 1.2121x; 1.2121x over previous
//
#include <hip/hip_runtime.h>
#include <hip/hip_bf16.h>
#include <cstdint>
#include <cstddef>

// ---------------- sizes ----------------
#define N1 442368   // 48*96*96 spatial (s1)
#define N2 55296    // 24*48*48 spatial (p2, s2)
#define N3 6912     // 12*24*24 spatial (p3, s3)

// padded fp64 feature layouts; rows are x-parity de-interleaved: [evens][odds]
#define PZ1 9409    // 97*97
#define PN1 461041  // 49*97*97
#define PV1 461041
#define PZ2 2401    // 49*49
#define PN2 60025   // 25*49*49
#define PV2 60025

// logical x -> de-interleaved slot
#define MAP1(x) (((x) & 1) ? 49 + ((x) >> 1) : ((x) >> 1))
#define MAP2(x) (((x) & 1) ? 25 + ((x) >> 1) : ((x) >> 1))

#define KCAND 512
#define CAP   4096

// ---------------- helpers ----------------
__device__ __forceinline__ unsigned long long f2key64(double f) {
  unsigned long long b = (unsigned long long)__double_as_longlong(f);
  return (b & 0x8000000000000000ULL) ? ~b : (b | 0x8000000000000000ULL);
}
__device__ __forceinline__ unsigned f2key32(float f) {
  unsigned b = __float_as_uint(f);
  return (b & 0x80000000u) ? ~b : (b | 0x80000000u);
}

// ---------------- weight pre-conversion to fp64, consumer layouts ----------------
// seg0 wd1[t*16+c]            = c1w[c*27+t]                       (432)
// seg1 wd2[((g*16+ci)*27+t)*8+c] = c2w[((g*8+c)*16+ci)*27+t]      (13824)  g in 0..3
// seg2 wd3[(((gi)*16+ci)*27+t)*4+c] = c3w[((g*4+c)*32+cig*16+ci)*27+t] (55296) gi=cig*16+g? see below
// seg3 wl1[ci*32+c] = l1w[c*16+ci]  (512)
// seg4 wl2[ci*32+c] = l2w[c*32+ci]  (1024)
// seg5 wl3[ci*32+c] = l3w[c*64+ci]  (2048)
__global__ void convert_k(const float* __restrict__ c1w, const float* __restrict__ c2w,
                          const float* __restrict__ c3w, const float* __restrict__ l1w,
                          const float* __restrict__ l2w, const float* __restrict__ l3w,
                          double* __restrict__ wd1, double* __restrict__ wd2,
                          double* __restrict__ wd3, double* __restrict__ wl1,
                          double* __restrict__ wl2, double* __restrict__ wl3) {
  int seg = blockIdx.y;
  int i = blockIdx.x * 256 + threadIdx.x;
  if (seg == 0) {
    if (i < 432) { int c = i & 15, t = i >> 4; wd1[i] = (double)c1w[c * 27 + t]; }
  } else if (seg == 1) {
    if (i < 13824) {
      int c = i & 7, t = (i >> 3) % 27, ci = (i / 216) & 15, g = i / 3456;
      wd2[i] = (double)c2w[((g * 8 + c) * 16 + ci) * 27 + t];
    }
  } else if (seg == 2) {
    if (i < 55296) {
      // block index gi = blockIdx.y in conv3 decodes g=gi&15, cig=gi>>4; weights contiguous per gi
      int c = i & 3, t = (i >> 2) % 27, ci = (i / 108) & 15, gi = i / 1728;
      int g = gi & 15, cig = gi >> 4;
      wd3[i] = (double)c3w[((g * 4 + c) * 32 + cig * 16 + ci) * 27 + t];
    }
  } else if (seg == 3) {
    if (i < 512) { int c = i & 31, ci = i >> 5; wl1[i] = (double)l1w[c * 16 + ci]; }
  } else if (seg == 4) {
    if (i < 1024) { int c = i & 31, ci = i >> 5; wl2[i] = (double)l2w[c * 32 + ci]; }
  } else {
    if (i < 2048) { int c = i & 31, ci = i >> 5; wl3[i] = (double)l3w[c * 64 + ci]; }
  }
}

// ---------------- conv1: 1->16ch, uniform-weight s_loads, no LDS ----------------
__global__ __launch_bounds__(256) void conv1_k(const float* __restrict__ x, const double* __restrict__ wd1,
                                               const float* __restrict__ b, double* __restrict__ f1) {
  int v = blockIdx.x * 256 + threadIdx.x;
  if (v >= PV1) return;
  int z = v / PZ1; int r = v % PZ1; int y = r / 97; int xo = r % 97;
  int ov = z * PZ1 + y * 97 + MAP1(xo);
  if (z >= 48 || y >= 96 || xo >= 96) {
#pragma unroll
    for (int c = 0; c < 16; c++) f1[(size_t)c * PN1 + ov] = 0.0;
    return;
  }
  float val[27];
#pragma unroll
  for (int dz = 0; dz < 3; dz++)
#pragma unroll
    for (int dy = 0; dy < 3; dy++)
#pragma unroll
      for (int dx = 0; dx < 3; dx++) {
        int zi = 2 * z + dz, yi = 2 * y + dy, xi = 2 * xo + dx;
        bool ok = (zi < 96) & (yi < 192) & (xi < 192);
        int zc = min(zi, 95), yc = min(yi, 191), xc = min(xi, 191);
        float t = x[(zc * 192 + yc) * 192 + xc];
        val[(dz * 3 + dy) * 3 + dx] = ok ? t : 0.0f;
      }
  double acc[16];
#pragma unroll
  for (int c = 0; c < 16; c++) acc[c] = (double)b[c];
#pragma unroll
  for (int t = 0; t < 27; t++) {
    double vv = (double)val[t];
#pragma unroll
    for (int c = 0; c < 16; c++) acc[c] = fma(vv, wd1[t * 16 + c], acc[c]);
  }
#pragma unroll
  for (int c = 0; c < 16; c++) f1[(size_t)c * PN1 + ov] = fmax(acc[c], 0.0);
}

// ---------------- conv2: 16->32ch; gridDim.y=4 groups of 8; s_load weights, no LDS ----------------
__global__ __launch_bounds__(256) void conv2_k(const double* __restrict__ f1, const double* __restrict__ wd2,
                                               const float* __restrict__ b, double* __restrict__ f2) {
  int g = blockIdx.y;
  int v = blockIdx.x * 256 + threadIdx.x;
  if (v >= PV2) return;
  int z = v / PZ2; int r = v % PZ2; int y = r / 49; int xo = r % 49;
  int ov = z * PZ2 + y * 49 + MAP2(xo);
  if (z >= 24 || y >= 48 || xo >= 48) {
#pragma unroll
    for (int c = 0; c < 8; c++) f2[(size_t)(g * 8 + c) * PN2 + ov] = 0.0;
    return;
  }
  double acc[8];
#pragma unroll
  for (int c = 0; c < 8; c++) acc[c] = (double)b[g * 8 + c];
  const double* wp = wd2 + (size_t)g * 3456;  // [ci][t][c8], block-uniform
  const double* base = f1 + (size_t)(2 * z) * PZ1 + (2 * y) * 97;
  for (int ci = 0; ci < 16; ci++) {
    const double* fp = base + (size_t)ci * PN1;
    double vals[27];
#pragma unroll
    for (int dz = 0; dz < 3; dz++)
#pragma unroll
      for (int dy = 0; dy < 3; dy++) {
        const double* row = fp + dz * PZ1 + dy * 97;
        int o = (dz * 3 + dy) * 3;
        vals[o + 0] = row[xo];
        vals[o + 1] = row[49 + xo];
        vals[o + 2] = row[xo + 1];
      }
#pragma unroll
    for (int t = 0; t < 27; t++) {
      double vv = vals[t];
      const double* w8 = wp + (ci * 27 + t) * 8;
#pragma unroll
      for (int c = 0; c < 8; c++) acc[c] = fma(vv, w8[c], acc[c]);
    }
  }
#pragma unroll
  for (int c = 0; c < 8; c++) f2[(size_t)(g * 8 + c) * PN2 + ov] = fmax(acc[c], 0.0);
}

// ---------------- conv3: 32->64ch; gridDim.y=32: g=gi&15 (4 couts), cig=gi>>4 (ci half) ----------------
// partial sums to f3a (cig=0, +bias) / f3b (cig=1); p3_k does ReLU(f3a+f3b)
__global__ __launch_bounds__(256) void conv3_k(const double* __restrict__ f2, const double* __restrict__ wd3,
                                               const float* __restrict__ b, double* __restrict__ f3a,
                                               double* __restrict__ f3b) {
  int gi = blockIdx.y;
  int g = gi & 15, cig = gi >> 4;
  int v = blockIdx.x * 256 + threadIdx.x;
  if (v >= N3) return;
  int z = v / 576; int r = v % 576; int y = r / 24; int xo = r % 24;
  double acc[4];
#pragma unroll
  for (int c = 0; c < 4; c++) acc[c] = cig == 0 ? (double)b[g * 4 + c] : 0.0;
  const double* wp = wd3 + (size_t)gi * 1728;  // [ci16][t27][c4], block-uniform
  const double* base = f2 + (size_t)(cig * 16) * PN2 + (size_t)(2 * z) * PZ2 + (2 * y) * 49;
  for (int ci = 0; ci < 16; ci++) {
    const double* fp = base + (size_t)ci * PN2;
    double vals[27];
#pragma unroll
    for (int dz = 0; dz < 3; dz++)
#pragma unroll
      for (int dy = 0; dy < 3; dy++) {
        const double* row = fp + dz * PZ2 + dy * 49;
        int o = (dz * 3 + dy) * 3;
        vals[o + 0] = row[xo];
        vals[o + 1] = row[25 + xo];
        vals[o + 2] = row[xo + 1];
      }
#pragma unroll
    for (int t = 0; t < 27; t++) {
      double vv = vals[t];
      const double* w4 = wp + (ci * 27 + t) * 4;
#pragma unroll
      for (int c = 0; c < 4; c++) acc[c] = fma(vv, w4[c], acc[c]);
    }
  }
  double* dst = cig == 0 ? f3a : f3b;
#pragma unroll
  for (int c = 0; c < 4; c++) dst[(size_t)(g * 4 + c) * N3 + v] = acc[c];
}

// ---------------- p3 = l3(relu(f3a+f3b)); score3 ----------------
__global__ __launch_bounds__(256) void p3_k(const double* __restrict__ f3a, const double* __restrict__ f3b,
                                            const double* __restrict__ wl3,
                                            const float* __restrict__ b, double* __restrict__ p3d,
                                            float* __restrict__ p3f, double* __restrict__ s3) {
  int v = blockIdx.x * 256 + threadIdx.x;
  if (v >= N3) return;
  double acc[32];
#pragma unroll
  for (int c = 0; c < 32; c++) acc[c] = (double)b[c];
  for (int ci = 0; ci < 64; ci++) {
    double vv = fmax(f3a[(size_t)ci * N3 + v] + f3b[(size_t)ci * N3 + v], 0.0);
    const double* wp = wl3 + ci * 32;
#pragma unroll
    for (int c = 0; c < 32; c++) acc[c] = fma(vv, wp[c], acc[c]);
  }
  double m = -1e300;
#pragma unroll
  for (int c = 0; c < 32; c++) {
    p3d[(size_t)c * N3 + v] = acc[c];
    p3f[(size_t)c * N3 + v] = (float)acc[c];
    m = fmax(m, acc[c]);
  }
  s3[v] = m;
}

// ---------------- p2 = l2(f2) + up2(p3); score2 ----------------
__global__ __launch_bounds__(256) void p2_k(const double* __restrict__ f2, const double* __restrict__ wl2,
                                            const float* __restrict__ b, const double* __restrict__ p3d,
                                            double* __restrict__ p2d, float* __restrict__ p2f, double* __restrict__ s2) {
  int v = blockIdx.x * 256 + threadIdx.x;
  if (v >= N2) return;
  int z = v / (48 * 48); int r = v % (48 * 48); int y = r / 48; int xo = r % 48;
  int pidx = z * PZ2 + y * 49 + MAP2(xo);
  int up = ((z >> 1) * 24 + (y >> 1)) * 24 + (xo >> 1);
  double acc[32];
#pragma unroll
  for (int c = 0; c < 32; c++) acc[c] = (double)b[c];
  for (int ci = 0; ci < 32; ci++) {
    double vv = f2[(size_t)ci * PN2 + pidx];
    const double* wp = wl2 + ci * 32;
#pragma unroll
    for (int c = 0; c < 32; c++) acc[c] = fma(vv, wp[c], acc[c]);
  }
  double m = -1e300;
#pragma unroll
  for (int c = 0; c < 32; c++) {
    double o = acc[c] + p3d[(size_t)c * N3 + up];
    p2d[(size_t)c * N2 + v] = o;
    p2f[(size_t)c * N2 + v] = (float)o;
    m = fmax(m, o);
  }
  s2[v] = m;
}

// ---------------- p1 score only ----------------
__global__ __launch_bounds__(256) void p1_k(const double* __restrict__ f1, const double* __restrict__ wl1,
                                            const float* __restrict__ b, const double* __restrict__ p2d,
                                            double* __restrict__ s1) {
  int v = blockIdx.x * 256 + threadIdx.x;
  if (v >= N1) return;
  int z = v / (96 * 96); int r = v % (96 * 96); int y = r / 96; int xo = r % 96;
  int pidx = z * PZ1 + y * 97 + MAP1(xo);
  int up = ((z >> 1) * 48 + (y >> 1)) * 48 + (xo >> 1);
  double acc[32];
#pragma unroll
  for (int c = 0; c < 32; c++) acc[c] = (double)b[c];
  for (int ci = 0; ci < 16; ci++) {
    double vv = f1[(size_t)ci * PN1 + pidx];
    const double* wp = wl1 + ci * 32;
#pragma unroll
    for (int c = 0; c < 32; c++) acc[c] = fma(vv, wp[c], acc[c]);
  }
  double m = -1e300;
#pragma unroll
  for (int c = 0; c < 32; c++) m = fmax(m, acc[c] + p2d[(size_t)c * N2 + up]);
  s1[v] = m;
}

// ---------------- selection: two-pass 256-bin radix over fp32 key, batched over levels ----------------
__global__ void hist1_k(const double* __restrict__ s1, const double* __restrict__ s2,
                        const double* __restrict__ s3, unsigned* __restrict__ hist) {
  int L = blockIdx.y;
  const double* s = L == 0 ? s1 : (L == 1 ? s2 : s3);
  int n = L == 0 ? N1 : (L == 1 ? N2 : N3);
  unsigned* hg = hist + L * 256;
  __shared__ unsigned h[256];
  h[threadIdx.x] = 0;
  __syncthreads();
  for (int i = blockIdx.x * 256 + threadIdx.x; i < n; i += gridDim.x * 256)
    atomicAdd(&h[f2key32((float)s[i]) >> 24], 1u);
  __syncthreads();
  unsigned v = h[threadIdx.x];
  if (v) atomicAdd(&hg[threadIdx.x], v);
}

__global__ void hist2_k(const double* __restrict__ s1, const double* __restrict__ s2,
                        const double* __restrict__ s3, const unsigned* __restrict__ hist1,
                        unsigned* __restrict__ hist2) {
  int L = blockIdx.y;
  const double* s = L == 0 ? s1 : (L == 1 ? s2 : s3);
  int n = L == 0 ? N1 : (L == 1 ? N2 : N3);
  const unsigned* h1 = hist1 + L * 256;
  unsigned run = 0; unsigned b1 = 0;
  for (int i = 255; i >= 0; i--) {
    unsigned c = h1[i];
    if (run + c >= (unsigned)KCAND) { b1 = (unsigned)i; break; }
    run += c;
  }
  unsigned* hg = hist2 + L * 256;
  __shared__ unsigned h[256];
  h[threadIdx.x] = 0;
  __syncthreads();
  for (int i = blockIdx.x * 256 + threadIdx.x; i < n; i += gridDim.x * 256) {
    unsigned k = f2key32((float)s[i]);
    if ((k >> 24) == b1) atomicAdd(&h[(k >> 16) & 255u], 1u);
  }
  __syncthreads();
  unsigned v = h[threadIdx.x];
  if (v) atomicAdd(&hg[threadIdx.x], v);
}

__global__ void compact_k(const double* __restrict__ s1, const double* __restrict__ s2,
                          const double* __restrict__ s3, const unsigned* __restrict__ hist1,
                          const unsigned* __restrict__ hist2,
                          unsigned long long* __restrict__ ck, unsigned* __restrict__ cidx,
                          unsigned* __restrict__ cnt) {
  int L = blockIdx.y;
  const double* s = L == 0 ? s1 : (L == 1 ? s2 : s3);
  int n = L == 0 ? N1 : (L == 1 ? N2 : N3);
  const unsigned* h1 = hist1 + L * 256;
  const unsigned* h2 = hist2 + L * 256;
  unsigned run = 0; unsigned b1 = 0;
  for (int i = 255; i >= 0; i--) {
    unsigned c = h1[i];
    if (run + c >= (unsigned)KCAND) { b1 = (unsigned)i; break; }
    run += c;
  }
  unsigned b2 = 0;
  for (int i = 255; i >= 0; i--) {
    run += h2[i];
    if (run >= (unsigned)KCAND) { b2 = (unsigned)i; break; }
  }
  unsigned T = (b1 << 24) | (b2 << 16);
  for (int i = blockIdx.x * 256 + threadIdx.x; i < n; i += gridDim.x * 256) {
    double v = s[i];
    if (f2key32((float)v) >= T) {
      unsigned pos = atomicAdd(&cnt[L], 1u);
      if (pos < (unsigned)CAP) {
        ck[(size_t)L * CAP + pos] = f2key64(v);
        cidx[(size_t)L * CAP + pos] = (unsigned)i;
      }
    }
  }
}

__global__ void sort_k(const unsigned long long* __restrict__ ckA, const unsigned* __restrict__ cidxA,
                       const unsigned* __restrict__ cnt, uint2* __restrict__ topkA) {
  __shared__ unsigned long long k_[CAP];
  __shared__ unsigned x_[CAP];
  int L = blockIdx.x;
  const unsigned long long* ck = ckA + (size_t)L * CAP;
  const unsigned* cidx = cidxA + (size_t)L * CAP;
  uint2* topk = topkA + (size_t)L * KCAND;
  int t = threadIdx.x;
  unsigned m = cnt[L]; if (m > (unsigned)CAP) m = CAP;
  int sz = 512; while (sz < (int)m) sz <<= 1;
  for (int i = t; i < sz; i += 1024) {
    if (i < (int)m) { k_[i] = ck[i]; x_[i] = cidx[i]; }
    else            { k_[i] = 0ULL;  x_[i] = 0xFFFFFFFFu; }
  }
  __syncthreads();
  for (int kk = 2; kk <= sz; kk <<= 1) {
    for (int j = kk >> 1; j > 0; j >>= 1) {
      for (int i = t; i < sz; i += 1024) {
        int l = i ^ j;
        if (l > i) {
          unsigned long long ka = k_[i], kb = k_[l];
          unsigned ia = x_[i], ib = x_[l];
          bool b_first = (kb > ka) || (kb == ka && ib < ia);
          bool up = (i & kk) == 0;
          if (up == b_first) { k_[i] = kb; x_[i] = ib; k_[l] = ka; x_[l] = ia; }
        }
      }
      __syncthreads();
    }
  }
  if (t < KCAND) {
    unsigned long long key = k_[t];
    unsigned long long bb = (key >> 63) ? (key & 0x7FFFFFFFFFFFFFFFULL) : ~key;
    double sc = __longlong_as_double((long long)bb);
    topk[t] = make_uint2(x_[t], sc > 0.5 ? 1u : 0u);
  }
}

// ---------------- per-candidate cube stats + MLP; L=0 computes cubes on-the-fly ----------------
__global__ __launch_bounds__(64) void mlp_k(const uint2* __restrict__ topkA,
                                            const double* __restrict__ f1d, const double* __restrict__ p2d,
                                            const float* __restrict__ p2f, const float* __restrict__ p3f,
                                            const double* __restrict__ wl1, const float* __restrict__ l1b,
                                            const float* __restrict__ w1, const float* __restrict__ b1,
                                            const float* __restrict__ w2, const float* __restrict__ b2,
                                            float* __restrict__ out) {
  __shared__ double lhi[64];
  __shared__ double f1c[16 * 64];   // [ci][voxel]
  __shared__ double wsD[16 * 32];   // [ci][c]
  int L = blockIdx.y;
  int s = blockIdx.x;
  int D = 48 >> L, H = 96 >> L, W = 96 >> L;
  uint2 e = topkA[(size_t)L * KCAND + s];
  unsigned idx = e.x;
  double valid = e.y ? 1.0 : 0.0;
  int HW = H * W;
  int z = (int)(idx / (unsigned)HW);
  int r = (int)(idx % (unsigned)HW);
  int y = r / W; int x = r % W;
  int zs = min(max(z - 2, 0), D - 4);
  int ys = min(max(y - 2, 0), H - 4);
  int xs = min(max(x - 2, 0), W - 4);
  int t = threadIdx.x;
  int c = t & 31, h = t >> 5;
  double sum = 0.0, ss = 0.0;
  if (L == 0) {
    for (int i = t; i < 512; i += 64) wsD[i] = wl1[i];
    for (int i = t; i < 1024; i += 64) {
      int ci = i >> 6, v = i & 63;
      int dz = v >> 4, dy = (v >> 2) & 3, dx = v & 3;
      f1c[i] = f1d[(size_t)ci * PN1 + (zs + dz) * PZ1 + (ys + dy) * 97 + MAP1(xs + dx)];
    }
    __syncthreads();
    double bc = (double)l1b[c];
    for (int i = 0; i < 32; i++) {
      int vv = h * 32 + i;
      int dz = vv >> 4, dy = (vv >> 2) & 3, dx = vv & 3;
      int up = (((zs + dz) >> 1) * 48 + ((ys + dy) >> 1)) * 48 + ((xs + dx) >> 1);
      double val = bc + p2d[(size_t)c * N2 + up];
#pragma unroll
      for (int ci = 0; ci < 16; ci++)
        val = fma(f1c[ci * 64 + vv], wsD[ci * 32 + c], val);
      sum += val; ss = fma(val, val, ss);
    }
  } else {
    const float* p = (L == 1) ? p2f : p3f;
    const float* pc = p + (size_t)c * D * HW;
    for (int i = 0; i < 32; i++) {
      int vv = h * 32 + i;
      int dz = vv >> 4, dy = (vv >> 2) & 3, dx = vv & 3;
      double val = (double)pc[(zs + dz) * HW + (ys + dy) * W + (xs + dx)];
      sum += val; ss = fma(val, val, ss);
    }
  }
  sum += __shfl_xor(sum, 32);
  ss  += __shfl_xor(ss, 32);
  if (h == 0) {
    double mean = sum * (1.0 / 64.0);
    double var = ss * (1.0 / 64.0) - mean * mean;
    lhi[c] = mean;
    lhi[32 + c] = sqrt(var + 1e-6);
  }
  __syncthreads();
  double h0 = (double)b1[t], h1 = (double)b1[t + 64];
  for (int i = 0; i < 64; i++) {
    double li = lhi[i];
    h0 = fma(li, (double)w1[i * 128 + t], h0);
    h1 = fma(li, (double)w1[i * 128 + t + 64], h1);
  }
  h0 = fmax(h0, 0.0); h1 = fmax(h1, 0.0);
  double o0 = h0 * (double)w2[t * 2 + 0] + h1 * (double)w2[(t + 64) * 2 + 0];
  double o1 = h0 * (double)w2[t * 2 + 1] + h1 * (double)w2[(t + 64) * 2 + 1];
  for (int o = 1; o < 64; o <<= 1) { o0 += __shfl_xor(o0, o); o1 += __shfl_xor(o1, o); }
  if (t == 0) {
    out[((size_t)L * KCAND + s) * 2 + 0] = (float)((o0 + (double)b2[0]) * valid);
    out[((size_t)L * KCAND + s) * 2 + 1] = (float)((o1 + (double)b2[1]) * valid);
  }
}

// ---------------- launch ----------------
extern "C" void kernel_launch(void* const* d_in, const int* in_sizes, int n_in,
                              void* d_out, int out_size, void* d_ws, size_t ws_size,
                              hipStream_t stream) {
  const float* x   = (const float*)d_in[0];
  const float* c1w = (const float*)d_in[1];  const float* c1b = (const float*)d_in[2];
  const float* c2w = (const float*)d_in[3];  const float* c2b = (const float*)d_in[4];
  const float* c3w = (const float*)d_in[5];  const float* c3b = (const float*)d_in[6];
  const float* l1w = (const float*)d_in[7];  const float* l1b = (const float*)d_in[8];
  const float* l2w = (const float*)d_in[9];  const float* l2b = (const float*)d_in[10];
  const float* l3w = (const float*)d_in[11]; const float* l3b = (const float*)d_in[12];
  const float* w1  = (const float*)d_in[13]; const float* b1  = (const float*)d_in[14];
  const float* w2  = (const float*)d_in[15]; const float* b2  = (const float*)d_in[16];
  float* out = (float*)d_out;

  char* ws = (char*)d_ws;
  size_t off = 0;
  auto take = [&](size_t bytes) { size_t o = off; off = (off + bytes + 255) & ~(size_t)255; return o; };
  double* f1d = (double*)(ws + take((size_t)16 * PN1 * 8));
  double* f2d = (double*)(ws + take((size_t)32 * PN2 * 8));
  double* f3a = (double*)(ws + take((size_t)64 * N3 * 8));
  double* f3b = (double*)(ws + take((size_t)64 * N3 * 8));
  double* p2d = (double*)(ws + take((size_t)32 * N2 * 8));
  float*  p2f = (float*) (ws + take((size_t)32 * N2 * 4));
  double* p3d = (double*)(ws + take((size_t)32 * N3 * 8));
  float*  p3f = (float*) (ws + take((size_t)32 * N3 * 4));
  double* s1 = (double*)(ws + take((size_t)N1 * 8));
  double* s2 = (double*)(ws + take((size_t)N2 * 8));
  double* s3 = (double*)(ws + take((size_t)N3 * 8));
  double* wd1 = (double*)(ws + take(432 * 8));
  double* wd2 = (double*)(ws + take(13824 * 8));
  double* wd3 = (double*)(ws + take(55296 * 8));
  double* wl1 = (double*)(ws + take(512 * 8));
  double* wl2 = (double*)(ws + take(1024 * 8));
  double* wl3 = (double*)(ws + take(2048 * 8));
  size_t zOff = take((3 * 256 + 3 * 256 + 3) * 4);
  unsigned* hist1 = (unsigned*)(ws + zOff);
  unsigned* hist2 = hist1 + 3 * 256;
  unsigned* cnt   = hist2 + 3 * 256;
  unsigned long long* candKey = (unsigned long long*)(ws + take((size_t)3 * CAP * 8));
  unsigned* candIdx = (unsigned*)(ws + take((size_t)3 * CAP * 4));
  uint2* topk = (uint2*)(ws + take((size_t)3 * KCAND * 8));

  hipMemsetAsync(ws + zOff, 0, (3 * 256 + 3 * 256 + 3) * 4, stream);

  // weight conversion (fp64, consumer layouts)
  convert_k<<<dim3(216, 6), 256, 0, stream>>>(c1w, c2w, c3w, l1w, l2w, l3w,
                                              wd1, wd2, wd3, wl1, wl2, wl3);
  // encoder (fp64, uniform-weight scalar loads, no LDS)
  conv1_k<<<(PV1 + 255) / 256, 256, 0, stream>>>(x, wd1, c1b, f1d);
  conv2_k<<<dim3((PV2 + 255) / 256, 4), 256, 0, stream>>>(f1d, wd2, c2b, f2d);
  conv3_k<<<dim3((N3 + 255) / 256, 32), 256, 0, stream>>>(f2d, wd3, c3b, f3a, f3b);
  // FPN top-down
  p3_k<<<(N3 + 255) / 256, 256, 0, stream>>>(f3a, f3b, wl3, l3b, p3d, p3f, s3);
  p2_k<<<(N2 + 255) / 256, 256, 0, stream>>>(f2d, wl2, l2b, p3d, p2d, p2f, s2);
  p1_k<<<(N1 + 255) / 256, 256, 0, stream>>>(f1d, wl1, l1b, p2d, s1);

  // selection (batched across 3 levels)
  hist1_k<<<dim3(64, 3), 256, 0, stream>>>(s1, s2, s3, hist1);
  hist2_k<<<dim3(64, 3), 256, 0, stream>>>(s1, s2, s3, hist1, hist2);
  compact_k<<<dim3(112, 3), 256, 0, stream>>>(s1, s2, s3, hist1, hist2, candKey, candIdx, cnt);
  sort_k<<<3, 1024, 0, stream>>>(candKey, candIdx, cnt, topk);
  mlp_k<<<dim3(KCAND, 3), 64, 0, stream>>>(topk, f1d, p2d, p2f, p3f, wl1, l1b,
                                           w1, b1, w2, b2, out);
}